// Round 10
// baseline (155.540 us; speedup 1.0000x reference)
//
#include <hip/hip_runtime.h>
#include <hip/hip_bf16.h>
#include <stdint.h>
#include <stddef.h>

#define D_MODEL 4096
#define RANK    64
#define M_BLK   16
#define KC      128                  // fp32 k per chunk
#define NCHK    (D_MODEL / KC)       // 32
#define BUFB    8192                 // bytes per ring buffer (16 rows x 128 f32 x 4B)

typedef __attribute__((ext_vector_type(4)))  float f32x4;
typedef __attribute__((ext_vector_type(8)))  short bf16x8;

__device__ inline short f2bf1(float f) {
    union { __hip_bfloat16 t; short s; } c;
    c.t = __float2bfloat16(f);
    return c.s;
}
__device__ inline uint32_t pkbf(float a, float b) {
    union { __hip_bfloat162 t; uint32_t u; } c;
    c.t = __float22bfloat162_rn(make_float2(a, b));
    return c.u;
}

// global -> LDS direct copy, 16 B per lane. LDS base wave-uniform; HW writes
// lds_base + lane*16. Global address is per-lane.
__device__ inline void gload_lds16(const void* g, void* l) {
    __builtin_amdgcn_global_load_lds(
        (const __attribute__((address_space(1))) uint32_t*)g,
        (__attribute__((address_space(3))) uint32_t*)l, 16, 0, 0);
}

// ---------------------------------------------------------------------------
// Dequant + pack both weights into 16x16x32 MFMA B-fragment order (R6 layout).
// apk: apk[((kb*4+n)*64+l)*8+j]  = a[16n+(l&15)][kb*32+(l>>4)*8+j]   kb 0..127
// bpk: bpk[((cb*2+ks)*64+l)*8+j] = b[cb*16+(l&15)][ks*32+(l>>4)*8+j] cb 0..255
// ---------------------------------------------------------------------------
__global__ __launch_bounds__(256) void dequant_pack_kernel(
        const int* __restrict__ qa, const float* __restrict__ qas,
        const int* __restrict__ qb, const float* __restrict__ qbs,
        short* __restrict__ apk, short* __restrict__ bpk) {
    const int idx = blockIdx.x * 256 + threadIdx.x;   // 0..32767
    const int l = idx & 63, t = idx >> 6;             // t: 0..511
    {   // a-side: t -> (kb 0..127, n 0..3)
        const int n = t & 3, kb = t >> 2;
        const int r = 16 * n + (l & 15);
        const int kbase = kb * 32 + ((l >> 4) << 3);
        const int* q = qa + (size_t)r * D_MODEL + kbase;
        const float s = qas[r * (D_MODEL / 32) + kb];
        bf16x8 o;
        #pragma unroll
        for (int j = 0; j < 8; ++j) o[j] = f2bf1((float)q[j] * s);
        *(bf16x8*)(apk + (size_t)idx * 8) = o;
    }
    {   // b-side: t -> (cb 0..255, ks 0..1)
        const int ks = t & 1, cb = t >> 1;
        const int d = cb * 16 + (l & 15);
        const int rbase = ks * 32 + ((l >> 4) << 3);
        const int* q = qb + (size_t)d * RANK + rbase;
        const float s = qbs[d * 2 + ks];
        bf16x8 o;
        #pragma unroll
        for (int j = 0; j < 8; ++j) o[j] = f2bf1((float)q[j] * s);
        *(bf16x8*)(bpk + (size_t)idx * 8) = o;
    }
}

// ---------------------------------------------------------------------------
// Fused P/C kernel, 4 desynced domains per CU. Block = 16 rows, 256 thr =
// 2 producer + 2 consumer waves, grid T/16 = 1024 -> 4 blocks/CU (LDS 34.8 KB).
// Ring schedule (race-free, as R9): issue 0,1,2; iter i: wait(chunk i) ->
// barrier -> issue i+3. Consumer apk fragments double-buffered: chunk i+1's
// L2 loads issued BEFORE barrier i, consumed from registers in window i+1.
// LDS x layout: row r at r*512, 32 16B-slots; slot s holds k-group s^(r&7)
// (producers pre-swizzle the GLOBAL source; consumers XOR on read).
// ---------------------------------------------------------------------------
__global__ __launch_bounds__(256, 4) void fused_kernel(
        const float* __restrict__ x, const short* __restrict__ apk,
        const short* __restrict__ bpk, float* __restrict__ out) {
    __shared__ __align__(16) char smem[4 * BUFB + 2048];
    float* red   = (float*)smem;                 // [2][16][68] overlay, 8704 B
    char*  h_lds = smem + 4 * BUFB;              // [16][64] bf16, slot-swizzled

    const int tid  = threadIdx.x;
    const int lane = tid & 63;
    const int wave = tid >> 6;
    const int rb   = blockIdx.x * M_BLK;
    const float* xb = x + (size_t)rb * D_MODEL;

    f32x4 acc[4];
    #pragma unroll
    for (int n = 0; n < 4; ++n) acc[n] = (f32x4){0.f, 0.f, 0.f, 0.f};

    if (wave < 2) {
        // ================= producers (waves 0,1) =================
        // instr jj covers rows (wave*4+jj)*2 + (lane>>5); slot lane&31;
        // global k-group = (lane&31) ^ (row&7)  (pre-swizzle).
        #define ISSUE_CHUNK(c)                                                  \
        {                                                                       \
            char* ldsb = smem + ((c) & 3) * BUFB + (wave * 4) * 1024;           \
            _Pragma("unroll")                                                   \
            for (int jj = 0; jj < 4; ++jj) {                                    \
                const int rw = (wave * 4 + jj) * 2 + (lane >> 5);               \
                const int k4 = ((lane & 31) ^ (rw & 7)) << 2;                   \
                const float* src = xb + (size_t)rw * D_MODEL + (c) * KC + k4;   \
                gload_lds16(src, ldsb + jj * 1024);                             \
            }                                                                   \
        }
        ISSUE_CHUNK(0)
        ISSUE_CHUNK(1)
        ISSUE_CHUNK(2)
        for (int i = 0; i < NCHK; ++i) {
            // chunk i landed; keep chunks i+1, i+2 (4 instr each) in flight
            if (i < NCHK - 2)       asm volatile("s_waitcnt vmcnt(8)" ::: "memory");
            else if (i == NCHK - 2) asm volatile("s_waitcnt vmcnt(4)" ::: "memory");
            else                    asm volatile("s_waitcnt vmcnt(0)" ::: "memory");
            __builtin_amdgcn_s_barrier();
            asm volatile("" ::: "memory");
            if (i + 3 < NCHK) ISSUE_CHUNK(i + 3)
        }
        #undef ISSUE_CHUNK
    } else {
        // ================= consumers (waves 2,3) =================
        const int cw = wave - 2;                 // 0,1: k-64 slice within chunk
        const int row = lane & 15;
        bf16x8 bcur[8], bnxt[8];
        #pragma unroll
        for (int kb = 0; kb < 2; ++kb)
            #pragma unroll
            for (int n = 0; n < 4; ++n)
                bcur[kb * 4 + n] = *(const bf16x8*)(apk +
                    ((size_t)((cw * 2 + kb) * 4 + n) * 64 + lane) * 8);
        for (int i = 0; i < NCHK; ++i) {
            if (i + 1 < NCHK) {      // prefetch next chunk's apk frags (L2)
                const int kb0 = (i + 1) * 4 + cw * 2;
                #pragma unroll
                for (int kb = 0; kb < 2; ++kb)
                    #pragma unroll
                    for (int n = 0; n < 4; ++n)
                        bnxt[kb * 4 + n] = *(const bf16x8*)(apk +
                            ((size_t)((kb0 + kb) * 4 + n) * 64 + lane) * 8);
            }
            asm volatile("" ::: "memory");
            __builtin_amdgcn_s_barrier();
            asm volatile("" ::: "memory");
            const char* bufc = smem + (i & 3) * BUFB;
            #pragma unroll
            for (int kb = 0; kb < 2; ++kb) {
                const int g0 = (cw * 2 + kb) * 8 + ((lane >> 4) << 1);
                f32x4 lo = *(const f32x4*)(bufc + row * 512 + ((g0 ^ (row & 7)) << 4));
                f32x4 hi = *(const f32x4*)(bufc + row * 512 + (((g0 + 1) ^ (row & 7)) << 4));
                bf16x8 af;
                uint32_t* p = (uint32_t*)&af;
                p[0] = pkbf(lo[0], lo[1]); p[1] = pkbf(lo[2], lo[3]);
                p[2] = pkbf(hi[0], hi[1]); p[3] = pkbf(hi[2], hi[3]);
                #pragma unroll
                for (int n = 0; n < 4; ++n)
                    acc[n] = __builtin_amdgcn_mfma_f32_16x16x32_bf16(
                        af, bcur[kb * 4 + n], acc[n], 0, 0, 0);
            }
            #pragma unroll
            for (int u = 0; u < 8; ++u) bcur[u] = bnxt[u];
        }
    }

    __syncthreads();                      // ring fully consumed; reuse as red

    // ---- phase 2: consumer partials -> red, all-thread reduce -> h_lds ----
    if (wave >= 2) {
        const int cw = wave - 2;
        const int r4 = (lane >> 4) << 2;
        #pragma unroll
        for (int n = 0; n < 4; ++n)
            #pragma unroll
            for (int j = 0; j < 4; ++j)
                red[(cw * 16 + r4 + j) * 68 + n * 16 + (lane & 15)] = acc[n][j];
    }
    __syncthreads();
    {
        const int r = tid >> 4, q = tid & 15;      // row 0..15, col-quad q
        const int c0 = q << 2;
        float s[4];
        #pragma unroll
        for (int u = 0; u < 4; ++u)
            s[u] = red[(0 * 16 + r) * 68 + c0 + u] + red[(1 * 16 + r) * 68 + c0 + u];
        uint2 o;
        o.x = pkbf(s[0], s[1]); o.y = pkbf(s[2], s[3]);
        const int slot = q >> 1, half = q & 1;
        *(uint2*)(h_lds + r * 128 + ((slot ^ (r & 7)) << 4) + (half << 3)) = o;
    }
    __syncthreads();

    // ---- phase 3: out[16][4096] = h @ b^T; wave w -> cols [w*1024, +1024) ----
    const int row = lane & 15;
    const int r4  = (lane >> 4) << 2;
    bf16x8 hf[2];
    #pragma unroll
    for (int ks = 0; ks < 2; ++ks) {
        const int slot = ks * 4 + (lane >> 4);
        hf[ks] = *(const bf16x8*)(h_lds + row * 128 + ((slot ^ (row & 7)) << 4));
    }

    #pragma unroll 4
    for (int n = 0; n < 64; ++n) {
        const int cb = wave * 64 + n;              // 16-col tile index 0..255
        f32x4 a2 = (f32x4){0.f, 0.f, 0.f, 0.f};
        #pragma unroll
        for (int ks = 0; ks < 2; ++ks) {
            bf16x8 bf = *(const bf16x8*)(bpk + ((size_t)(cb * 2 + ks) * 64 + lane) * 8);
            a2 = __builtin_amdgcn_mfma_f32_16x16x32_bf16(hf[ks], bf, a2, 0, 0, 0);
        }
        const int col = cb * 16 + row;
        #pragma unroll
        for (int j = 0; j < 4; ++j)
            out[(size_t)(rb + r4 + j) * D_MODEL + col] = a2[j];
    }
}

// ---------------------------------------------------------------------------
extern "C" void kernel_launch(void* const* d_in, const int* in_sizes, int n_in,
                              void* d_out, int out_size, void* d_ws, size_t ws_size,
                              hipStream_t stream) {
    (void)n_in; (void)out_size; (void)ws_size;
    const float* x   = (const float*)d_in[0];
    const int*   qa  = (const int*)d_in[1];
    const float* qas = (const float*)d_in[2];
    const int*   qb  = (const int*)d_in[3];
    const float* qbs = (const float*)d_in[4];
    float* out = (float*)d_out;

    const int T = in_sizes[0] / D_MODEL;   // 16384

    short* apk = (short*)d_ws;                       // 64*4096 bf16 packed
    short* bpk = apk + (size_t)RANK * D_MODEL;       // 4096*64 bf16 packed

    dequant_pack_kernel<<<128, 256, 0, stream>>>(qa, qas, qb, qbs, apk, bpk);
    fused_kernel<<<T / M_BLK, 256, 0, stream>>>(x, apk, bpk, out);
}

// Round 11
// 124.141 us; speedup vs baseline: 1.2529x; 1.2529x over previous
//
#include <hip/hip_runtime.h>
#include <hip/hip_bf16.h>
#include <stdint.h>
#include <stddef.h>

#define D_MODEL 4096
#define RANK    64
#define KC      512                 // fp32 k-elements per chunk
#define NCH     (D_MODEL / KC)      // 8
#define M_BLK   32

typedef __attribute__((ext_vector_type(4)))  float f32x4;
typedef __attribute__((ext_vector_type(16))) float f32x16;
typedef __attribute__((ext_vector_type(8)))  short bf16x8;

__device__ inline short f2bf1(float f) {
    union { __hip_bfloat16 t; short s; } c;
    c.t = __float2bfloat16(f);
    return c.s;
}
__device__ inline uint32_t pkbf(float a, float b) {
    union { __hip_bfloat162 t; uint32_t u; } c;
    c.t = __float22bfloat162_rn(make_float2(a, b));
    return c.u;
}

// ---------------------------------------------------------------------------
// Dequant + pack both weights into MFMA-fragment order (R4 layouts).
// apk (16x16x32 B-frag): apk[((kb*4+n)*64+l)*8+j] = a[16n+(l&15)][kb*32+(l>>4)*8+j]
// bpk (32x32x16 B-frag): bpk[((cb*4+ks)*64+l)*8+j] = b[cb*32+(l&31)][ks*16+(l>>5)*8+j]
// Regular stores: apk/bpk are re-read every call and want L2/L3 residency.
// ---------------------------------------------------------------------------
__global__ __launch_bounds__(256) void dequant_pack_kernel(
        const int* __restrict__ qa, const float* __restrict__ qas,
        const int* __restrict__ qb, const float* __restrict__ qbs,
        short* __restrict__ apk, short* __restrict__ bpk) {
    const int idx = blockIdx.x * 256 + threadIdx.x;   // 0..32767
    const int l = idx & 63, t = idx >> 6;             // t: 0..511
    {   // a-side: t -> (kb 0..127, n 0..3)
        const int n = t & 3, kb = t >> 2;
        const int r = 16 * n + (l & 15);
        const int kbase = kb * 32 + ((l >> 4) << 3);
        const int* q = qa + (size_t)r * D_MODEL + kbase;
        const float s = qas[r * (D_MODEL / 32) + kb];
        bf16x8 o;
        #pragma unroll
        for (int j = 0; j < 8; ++j) o[j] = f2bf1((float)q[j] * s);
        *(bf16x8*)(apk + (size_t)idx * 8) = o;
    }
    {   // b-side: t -> (cb 0..127, ks 0..3)
        const int ks = t & 3, cb = t >> 2;
        const int d = cb * 32 + (l & 31);
        const int rbase = ks * 16 + ((l >> 5) << 3);
        const int* q = qb + (size_t)d * RANK + rbase;
        const float s = qbs[d * 2 + (ks >> 1)];
        bf16x8 o;
        #pragma unroll
        for (int j = 0; j < 8; ++j) o[j] = f2bf1((float)q[j] * s);
        *(bf16x8*)(bpk + (size_t)idx * 8) = o;
    }
}

// ---------------------------------------------------------------------------
// Fused kernel (R4 structure, best measured): block = 32 rows, 512 thr
// (8 waves), grid T/32 = 512. Double-buffered XOR-swizzled LDS stage of x,
// 8-wave split-K 16x16x32 MFMA, one barrier per chunk, 2-chunk prefetch.
// Phase 2: fp32 cross-wave reduce -> h bf16 in LDS (h never in HBM).
// Phase 3: out = h @ b^T, 32x32x16 MFMA, NON-TEMPORAL stores: out is
// write-once never-read -> nt keeps it out of L3 so x stays L3-resident
// across replays (out-allocation was evicting ~50% of x; FETCH_SIZE 137MB).
// ---------------------------------------------------------------------------
__global__ __launch_bounds__(512, 4) void fused_kernel(
        const float* __restrict__ x, const short* __restrict__ apk,
        const short* __restrict__ bpk, float* __restrict__ out) {
    // smem: stage double buffer 2 x (32 rows x 512 bf16) = 65536 B,
    //       overlaid by red[4][32][68] f32 (34816 B) in phase 2;
    //       h_lds 32x80 bf16 = 5120 B after the stage region.
    __shared__ __align__(16) char smem[65536 + 5120];
    float* red   = (float*)smem;
    short* h_lds = (short*)(smem + 65536);

    const int tid  = threadIdx.x;
    const int lane = tid & 63;
    const int wave = tid >> 6;
    const int rb   = blockIdx.x * M_BLK;

    const int srow = tid >> 7;               // 0..3
    const int scol = (tid & 127) << 2;       // float col 0,4,...,508
    const float* xb = x + (size_t)rb * D_MODEL;

    // ---- prologue: stage chunk 0, prefetch chunk 1 ----
    f32x4 xr[8];
    #pragma unroll
    for (int r = 0; r < 8; ++r)
        xr[r] = *(const f32x4*)(xb + (size_t)(r * 4 + srow) * D_MODEL + scol);
    #pragma unroll
    for (int r = 0; r < 8; ++r) {
        const int row = r * 4 + srow;
        int byte = row * 1024 + (scol << 1);
        byte ^= (row & 7) << 4;
        union { uint32_t w[2]; uint2 u; } p;
        p.w[0] = pkbf(xr[r][0], xr[r][1]);
        p.w[1] = pkbf(xr[r][2], xr[r][3]);
        *(uint2*)(smem + byte) = p.u;
    }
    #pragma unroll
    for (int r = 0; r < 8; ++r)
        xr[r] = *(const f32x4*)(xb + (size_t)(r * 4 + srow) * D_MODEL + KC + scol);
    __syncthreads();

    f32x4 acc[2][4];
    #pragma unroll
    for (int m = 0; m < 2; ++m)
        #pragma unroll
        for (int n = 0; n < 4; ++n)
            acc[m][n] = (f32x4){0.f, 0.f, 0.f, 0.f};

    // ---- main K loop: one barrier per chunk ----
    for (int c = 0; c < NCH; ++c) {
        const char* sb = smem + (c & 1) * 32768;
        #pragma unroll
        for (int ks = 0; ks < 2; ++ks) {
            const int kin = wave * 64 + ks * 32 + ((lane >> 4) << 3);
            bf16x8 af[2];
            #pragma unroll
            for (int m = 0; m < 2; ++m) {
                const int row = m * 16 + (lane & 15);
                int byte = row * 1024 + (kin << 1);
                byte ^= (row & 7) << 4;
                af[m] = *(const bf16x8*)(sb + byte);
            }
            const int kbg = c * 16 + wave * 2 + ks;      // global 32-k block
            #pragma unroll
            for (int n = 0; n < 4; ++n) {
                bf16x8 bf = *(const bf16x8*)(apk + ((size_t)((kbg * 4 + n) * 64 + lane) << 3));
                #pragma unroll
                for (int m = 0; m < 2; ++m)
                    acc[m][n] = __builtin_amdgcn_mfma_f32_16x16x32_bf16(
                        af[m], bf, acc[m][n], 0, 0, 0);
            }
        }
        if (c < NCH - 1) {
            char* sw = smem + ((c + 1) & 1) * 32768;
            #pragma unroll
            for (int r = 0; r < 8; ++r) {
                const int row = r * 4 + srow;
                int byte = row * 1024 + (scol << 1);
                byte ^= (row & 7) << 4;
                union { uint32_t w[2]; uint2 u; } p;
                p.w[0] = pkbf(xr[r][0], xr[r][1]);
                p.w[1] = pkbf(xr[r][2], xr[r][3]);
                *(uint2*)(sw + byte) = p.u;
            }
            if (c < NCH - 2) {
                #pragma unroll
                for (int r = 0; r < 8; ++r)
                    xr[r] = *(const f32x4*)(xb + (size_t)(r * 4 + srow) * D_MODEL
                                            + (size_t)(c + 2) * KC + scol);
            }
        }
        __syncthreads();
    }

    // ---- phase 2: cross-wave reduction (red overlays stage) ----
    const int r4 = (lane >> 4) << 2;
    if (wave < 4) {
        #pragma unroll
        for (int m = 0; m < 2; ++m)
            #pragma unroll
            for (int n = 0; n < 4; ++n)
                #pragma unroll
                for (int j = 0; j < 4; ++j)
                    red[(wave * 32 + m * 16 + r4 + j) * 68 + n * 16 + (lane & 15)] =
                        acc[m][n][j];
    }
    __syncthreads();
    if (wave >= 4) {
        #pragma unroll
        for (int m = 0; m < 2; ++m)
            #pragma unroll
            for (int n = 0; n < 4; ++n)
                #pragma unroll
                for (int j = 0; j < 4; ++j)
                    red[((wave - 4) * 32 + m * 16 + r4 + j) * 68 + n * 16 + (lane & 15)] +=
                        acc[m][n][j];
    }
    __syncthreads();
    for (int e = tid; e < 32 * 64; e += 512) {
        const int r = e >> 6, cc = e & 63;
        float s = red[(0 * 32 + r) * 68 + cc] + red[(1 * 32 + r) * 68 + cc]
                + red[(2 * 32 + r) * 68 + cc] + red[(3 * 32 + r) * 68 + cc];
        h_lds[r * 80 + cc] = f2bf1(s);
    }
    __syncthreads();

    // ---- phase 3: out[32][4096] = h @ b^T; wave w -> cols [w*512, +512) ----
    bf16x8 hf[4];
    #pragma unroll
    for (int ks = 0; ks < 4; ++ks)
        hf[ks] = *(const bf16x8*)(h_lds + (lane & 31) * 80 + ks * 16 + ((lane >> 5) << 3));

    #pragma unroll
    for (int n = 0; n < 16; ++n) {
        const int cb32 = wave * 16 + n;
        const int col  = cb32 * 32 + (lane & 31);
        f32x16 a2;
        #pragma unroll
        for (int j = 0; j < 16; ++j) a2[j] = 0.f;
        #pragma unroll
        for (int ks = 0; ks < 4; ++ks) {
            bf16x8 bf = *(const bf16x8*)(bpk + ((size_t)((cb32 * 4 + ks) * 64 + lane) << 3));
            a2 = __builtin_amdgcn_mfma_f32_32x32x16_bf16(hf[ks], bf, a2, 0, 0, 0);
        }
        #pragma unroll
        for (int reg = 0; reg < 16; ++reg) {
            const int r = (reg & 3) + 8 * (reg >> 2) + ((lane >> 5) << 2);
            __builtin_nontemporal_store(a2[reg],
                &out[(size_t)(rb + r) * D_MODEL + col]);
        }
    }
}

// ---------------------------------------------------------------------------
extern "C" void kernel_launch(void* const* d_in, const int* in_sizes, int n_in,
                              void* d_out, int out_size, void* d_ws, size_t ws_size,
                              hipStream_t stream) {
    (void)n_in; (void)out_size; (void)ws_size;
    const float* x   = (const float*)d_in[0];
    const int*   qa  = (const int*)d_in[1];
    const float* qas = (const float*)d_in[2];
    const int*   qb  = (const int*)d_in[3];
    const float* qbs = (const float*)d_in[4];
    float* out = (float*)d_out;

    const int T = in_sizes[0] / D_MODEL;   // 16384

    short* apk = (short*)d_ws;                       // 64*4096 bf16 packed
    short* bpk = apk + (size_t)RANK * D_MODEL;       // 4096*64 bf16 packed

    dequant_pack_kernel<<<128, 256, 0, stream>>>(qa, qas, qb, qbs, apk, bpk);
    fused_kernel<<<T / M_BLK, 512, 0, stream>>>(x, apk, bpk, out);
}